// Round 17
// baseline (265.103 us; speedup 1.0000x reference)
//
#include <hip/hip_runtime.h>
#include <hip/hip_bf16.h>
#include <hip/hip_fp16.h>
#include <math.h>

#define NN 20000
#define EE 320000
#define GG 64
#define IND 256
#define HD 256
#define CC 2

typedef __hip_bfloat16 bf16;
typedef __attribute__((ext_vector_type(8))) short short8;
typedef __attribute__((ext_vector_type(4))) float f32x4;

__device__ __forceinline__ float b2f(bf16 x){ return __bfloat162float(x); }
__device__ __forceinline__ float bits2f(unsigned short b){
    union{ float f; unsigned u; } v; v.u = ((unsigned)b) << 16; return v.f;
}
__device__ __forceinline__ short f2bs(float x){
    union{ bf16 b; short s; } u; u.b = __float2bfloat16(x); return u.s;
}
// float load by code: 0=fp32, 1=bf16, 2=fp16
__device__ __forceinline__ float ldf3(const void* p, size_t i, int c){
    if (c == 1) return b2f(((const bf16*)p)[i]);
    if (c == 2) return __half2float(((const __half*)p)[i]);
    return ((const float*)p)[i];
}
__device__ __forceinline__ int idec(const void* p, int i, int c){
    if (c == 1) return (int)(((const long long*)p)[i]);
    if (c == 2) return (int)(((const float*)p)[i]);
    if (c == 3) return (int)__half2float(((const __half*)p)[i]);
    return ((const int*)p)[i];
}

// ---- merged dtype + int-format detection + counter zeroing ----
// blocks 0..2: int format of src/dst/gid; block 3: float dtypes; blocks 4+: zero counters
__global__ __launch_bounds__(256) void k_detect(const void* src, const void* dst,
                         const void* gid,
                         const unsigned short* h, const unsigned short* Wc,
                         const unsigned short* wg, const unsigned short* W1,
                         const unsigned short* W2, const unsigned short* bc,
                         int* icode, int* dcode, int* zero_base){
    int blk = blockIdx.x;
    if (blk >= 4){
        int idx = (blk-4)*256 + threadIdx.x;
        for (int i = idx; i < 3*NN; i += 60*256) zero_base[i] = 0;
        return;
    }
    if (blk < 3){
        if (threadIdx.x != 0) return;
        const void* buf = (blk == 0) ? src : (blk == 1) ? dst : gid;
        int n     = (blk == 2) ? NN : EE;
        int bound = (blk == 2) ? GG : NN;
        int ok64 = 1, ok32 = 1, okf32 = 1, okf16 = 1;
        const long long* p64 = (const long long*)buf;
        for (int i = 0; i < 64; i++){
            long long v = p64[n/8 + i];
            if (v < 0 || v >= (long long)bound) ok64 = 0;
        }
        const int* p32 = (const int*)buf;
        const unsigned* pu = (const unsigned*)buf;
        for (int i = 0; i < 64; i++){
            int v = p32[n/4 + i];
            if (v < 0 || v >= bound) ok32 = 0;
            float f = __uint_as_float(pu[n/4 + i]);
            if (!(f >= 0.f && f < (float)bound)) okf32 = 0;
        }
        const __half* ph = (const __half*)buf;
        for (int i = 0; i < 64; i++){
            float f = __half2float(ph[n/2 + i]);
            if (!(f >= 0.f && f < (float)bound)) okf16 = 0;
        }
        icode[blk] = ok64 ? 1 : (ok32 ? 0 : (okf32 ? 2 : (okf16 ? 3 : 0)));
    } else {
        int t = threadIdx.x; if (t >= 6) return;
        const unsigned short* p = t==0?h:t==1?Wc:t==2?wg:t==3?W1:t==4?W2:bc;
        int cb = 0, cf = 0, nz = 0;
        for (int i = 0; i < 128; i += 2){
            unsigned u = p[i];
            nz += (u != 0);
            int e8 = (u >> 7) & 0xFF;
            int e5 = (u >> 10) & 0x1F;
            cb += (e8 >= 100 && e8 <= 141);
            cf += (e5 >= 4 && e5 <= 22);
        }
        dcode[t] = (nz < 8) ? 0 : (cb >= 60) ? 1 : ((cf >= 60) ? 2 : 0);
    }
}

// decode gid + int degree counting
__global__ void k_prep(const void* src_r, const void* dst_r, const void* gid_r,
                       const int* __restrict__ icode,
                       int* __restrict__ gid_i,
                       int* cnt_out, int* cnt_in){
    int i = blockIdx.x*256 + threadIdx.x;
    if (i < NN) gid_i[i] = idec(gid_r, i, icode[2]);
    if (i >= EE) return;
    int s = idec(src_r, i, icode[0]);
    int d = idec(dst_r, i, icode[1]);
    if ((unsigned)s < NN) atomicAdd(&cnt_out[s], 1);
    if ((unsigned)d < NN) atomicAdd(&cnt_in[d], 1);
}

// single-block (1024 threads): rs arrays + scan -> rowst + per-graph ranges
__global__ __launch_bounds__(1024) void k_scan(const int* __restrict__ cnt_out,
                                               const int* __restrict__ cnt_in,
                                               const int* __restrict__ gid,
                                               float* rs_out, float* rs_in,
                                               int* __restrict__ row_start,
                                               int* gstart, int* gend){
    int t = threadIdx.x;
    for (int i = t; i < NN; i += 1024){
        rs_out[i] = rsqrtf(fmaxf((float)cnt_out[i], 1.f));
        rs_in[i]  = rsqrtf(fmaxf((float)cnt_in[i], 1.f));
    }
    __shared__ int part[1024];
    const int per = (NN + 1023)/1024;
    int lo = t*per, hi = min(lo+per, NN);
    int s = 0;
    for (int i = lo; i < hi; i++) s += cnt_in[i];
    part[t] = s; __syncthreads();
    for (int off = 1; off < 1024; off <<= 1){
        int v = (t >= off) ? part[t-off] : 0;
        __syncthreads();
        part[t] += v;
        __syncthreads();
    }
    int base = part[t] - s;
    for (int i = lo; i < hi; i++){ row_start[i] = base; base += cnt_in[i]; }
    if (t == 1023) row_start[NN] = part[1023];
    __shared__ int ls[GG+1];
    if (t <= GG){
        int a = 0, b = NN;
        while (a < b){
            int mid = (a + b) >> 1;
            if (gid[mid] < t) a = mid + 1; else b = mid;
        }
        ls[t] = a;
    }
    __syncthreads();
    if (t < GG){ gstart[t] = ls[t]; gend[t] = ls[t+1]; }
}

// fill CSR, decoding raw edges inline
__global__ void k_fill(const void* src_r, const void* dst_r,
                       const int* __restrict__ icode,
                       const int* __restrict__ row_start, int* __restrict__ cursor,
                       int* __restrict__ csr_src){
    int e = blockIdx.x*256 + threadIdx.x;
    if (e >= EE) return;
    int s = idec(src_r, e, icode[0]);
    int d = idec(dst_r, e, icode[1]);
    if ((unsigned)s >= NN || (unsigned)d >= NN) return;
    int pos = atomicAdd(&cursor[d], 1);
    csr_src[row_start[d] + pos] = s;
}

// W_conv[IN][HD] fp32 -> Wb[n][k] bf16 (fragment-friendly transpose)
__global__ void k_wprep(const void* __restrict__ W, const int* __restrict__ dcode,
                        bf16* __restrict__ Wb){
    int k = blockIdx.x;
    int n = threadIdx.x;
    Wb[(size_t)n*IND + k] = __float2bfloat16(ldf3(W, (size_t)k*HD + n, dcode[1]));
}

// LDS-free MFMA GEMM: hn[N,HD] = rs_out[n]*(h @ W_conv), 32 rows/block, 625 blocks.
__global__ __launch_bounds__(256) void k_gemm1m(const void* __restrict__ h,
                                                const bf16* __restrict__ Wb,
                                                const float* __restrict__ rs_out,
                                                const int* __restrict__ dcode,
                                                bf16* __restrict__ hn){
    int fh = dcode[0];
    int tid = threadIdx.x;
    int wave = tid >> 6, lane = tid & 63;
    int q = lane >> 4, mr = lane & 15;
    int row0 = blockIdx.x * 32;
    int ncol0 = wave * 64;
    f32x4 acc[2][4] = {};
    const float* hf = (const float*)h;
    #pragma unroll
    for (int k0 = 0; k0 < IND; k0 += 32){
        short8 a[2], b[4];
        if (fh == 0){
            #pragma unroll
            for (int mi = 0; mi < 2; mi++){
                int r = row0 + mi*16 + mr;
                const float4* p = (const float4*)(hf + (size_t)r*IND + k0 + q*8);
                float4 v0 = p[0], v1 = p[1];
                a[mi][0] = f2bs(v0.x); a[mi][1] = f2bs(v0.y);
                a[mi][2] = f2bs(v0.z); a[mi][3] = f2bs(v0.w);
                a[mi][4] = f2bs(v1.x); a[mi][5] = f2bs(v1.y);
                a[mi][6] = f2bs(v1.z); a[mi][7] = f2bs(v1.w);
            }
        } else {
            #pragma unroll
            for (int mi = 0; mi < 2; mi++){
                int r = row0 + mi*16 + mr;
                #pragma unroll
                for (int j = 0; j < 8; j++)
                    a[mi][j] = f2bs(ldf3(h, (size_t)r*IND + k0 + q*8 + j, fh));
            }
        }
        #pragma unroll
        for (int ni = 0; ni < 4; ni++)
            b[ni] = *reinterpret_cast<const short8*>(
                        Wb + (size_t)(ncol0 + ni*16 + mr)*IND + k0 + q*8);
        #pragma unroll
        for (int mi = 0; mi < 2; mi++)
            #pragma unroll
            for (int ni = 0; ni < 4; ni++)
                acc[mi][ni] = __builtin_amdgcn_mfma_f32_16x16x32_bf16(
                                  a[mi], b[ni], acc[mi][ni], 0, 0, 0);
    }
    #pragma unroll
    for (int mi = 0; mi < 2; mi++){
        int rowb = row0 + mi*16 + q*4;
        #pragma unroll
        for (int r = 0; r < 4; r++){
            int row = rowb + r;
            float rs = rs_out[row];
            #pragma unroll
            for (int ni = 0; ni < 4; ni++)
                hn[(size_t)row*HD + ncol0 + ni*16 + mr] =
                    __float2bfloat16(acc[mi][ni][r] * rs);
        }
    }
}

// fused gather + epilogue: one wave per dst node; 8-wide MLP unroll.
__global__ __launch_bounds__(256) void k_gather(const bf16* __restrict__ hn,
                                                const float* __restrict__ rs_in,
                                                const int* __restrict__ row_start,
                                                const int* __restrict__ csr_src,
                                                const void* __restrict__ b_conv,
                                                const void* __restrict__ w_gate,
                                                const void* __restrict__ b_gate,
                                                const int* __restrict__ dcode,
                                                float* __restrict__ hr,
                                                float* __restrict__ gate){
    int wave = threadIdx.x >> 6, lane = threadIdx.x & 63;
    int n = blockIdx.x*4 + wave;
    if (n >= NN) return;
    int lo = row_start[n], hi = row_start[n+1];
    float ax = 0.f, ay = 0.f, az = 0.f, aw = 0.f;
    int j = lo;
    for (; j + 8 <= hi; j += 8){
        int s0 = csr_src[j+0], s1 = csr_src[j+1], s2 = csr_src[j+2], s3 = csr_src[j+3];
        int s4 = csr_src[j+4], s5 = csr_src[j+5], s6 = csr_src[j+6], s7 = csr_src[j+7];
        ushort4 u0 = ((const ushort4*)(hn + (size_t)s0*HD))[lane];
        ushort4 u1 = ((const ushort4*)(hn + (size_t)s1*HD))[lane];
        ushort4 u2 = ((const ushort4*)(hn + (size_t)s2*HD))[lane];
        ushort4 u3 = ((const ushort4*)(hn + (size_t)s3*HD))[lane];
        ushort4 u4 = ((const ushort4*)(hn + (size_t)s4*HD))[lane];
        ushort4 u5 = ((const ushort4*)(hn + (size_t)s5*HD))[lane];
        ushort4 u6 = ((const ushort4*)(hn + (size_t)s6*HD))[lane];
        ushort4 u7 = ((const ushort4*)(hn + (size_t)s7*HD))[lane];
        ax += bits2f(u0.x)+bits2f(u1.x)+bits2f(u2.x)+bits2f(u3.x)
            + bits2f(u4.x)+bits2f(u5.x)+bits2f(u6.x)+bits2f(u7.x);
        ay += bits2f(u0.y)+bits2f(u1.y)+bits2f(u2.y)+bits2f(u3.y)
            + bits2f(u4.y)+bits2f(u5.y)+bits2f(u6.y)+bits2f(u7.y);
        az += bits2f(u0.z)+bits2f(u1.z)+bits2f(u2.z)+bits2f(u3.z)
            + bits2f(u4.z)+bits2f(u5.z)+bits2f(u6.z)+bits2f(u7.z);
        aw += bits2f(u0.w)+bits2f(u1.w)+bits2f(u2.w)+bits2f(u3.w)
            + bits2f(u4.w)+bits2f(u5.w)+bits2f(u6.w)+bits2f(u7.w);
    }
    for (; j < hi; j++){
        int s = csr_src[j];
        ushort4 u = ((const ushort4*)(hn + (size_t)s*HD))[lane];
        ax += bits2f(u.x); ay += bits2f(u.y); az += bits2f(u.z); aw += bits2f(u.w);
    }
    int db = dcode[5], fg = dcode[2];
    float rsn = rs_in[n];
    int c = lane*4;
    ax = fmaxf(fmaf(ax, rsn, ldf3(b_conv, c+0, db)), 0.f);
    ay = fmaxf(fmaf(ay, rsn, ldf3(b_conv, c+1, db)), 0.f);
    az = fmaxf(fmaf(az, rsn, ldf3(b_conv, c+2, db)), 0.f);
    aw = fmaxf(fmaf(aw, rsn, ldf3(b_conv, c+3, db)), 0.f);
    float4 v; v.x = ax; v.y = ay; v.z = az; v.w = aw;
    ((float4*)(hr + (size_t)n*HD))[lane] = v;
    float g = ax*ldf3(w_gate, c+0, fg) + ay*ldf3(w_gate, c+1, fg)
            + az*ldf3(w_gate, c+2, fg) + aw*ldf3(w_gate, c+3, fg);
    #pragma unroll
    for (int off = 32; off; off >>= 1) g += __shfl_down(g, off);
    if (lane == 0) gate[n] = g + ldf3(b_gate, 0, db);
}

// fused tail: per-graph softmax + attention-pool + classifier (one block per graph)
__global__ __launch_bounds__(256) void k_tail(const int* __restrict__ gstart,
                                              const int* __restrict__ gend,
                                              float* __restrict__ gate,
                                              const float* __restrict__ hr,
                                              const void* __restrict__ W1,
                                              const void* __restrict__ b1,
                                              const void* __restrict__ W2,
                                              const void* __restrict__ b2,
                                              const int* __restrict__ dcode,
                                              float* __restrict__ out0,
                                              float* __restrict__ out_att,
                                              float* __restrict__ out_hg){
    int g = blockIdx.x, t = threadIdx.x;
    int lo = gstart[g], hi = gend[g];
    __shared__ float sm[256];
    __shared__ float hs[256];
    // ---- softmax over gate[lo..hi) ----
    if (lo < hi){
        float m = -INFINITY;
        for (int n = lo + t; n < hi; n += 256) m = fmaxf(m, gate[n]);
        sm[t] = m; __syncthreads();
        for (int s = 128; s; s >>= 1){ if (t < s) sm[t] = fmaxf(sm[t], sm[t+s]); __syncthreads(); }
        m = sm[0]; __syncthreads();
        float acc = 0.f;
        for (int n = lo + t; n < hi; n += 256){
            float e = expf(gate[n] - m);
            gate[n] = e;
            acc += e;
        }
        sm[t] = acc; __syncthreads();
        for (int s = 128; s; s >>= 1){ if (t < s) sm[t] += sm[t+s]; __syncthreads(); }
        float inv = 1.f / sm[0];
        for (int n = lo + t; n < hi; n += 256){
            float a = gate[n] * inv;
            gate[n] = a;
            out_att[n] = a;
        }
    }
    __syncthreads();
    // ---- hg[g,c] = sum att[n]*hr[n,c], thread owns col c=t ----
    float acc = 0.f;
    int n = lo;
    for (; n + 4 <= hi; n += 4){
        float a0 = gate[n], a1 = gate[n+1], a2 = gate[n+2], a3 = gate[n+3];
        acc = fmaf(a0, hr[(size_t)n*HD + t], acc);
        acc = fmaf(a1, hr[(size_t)(n+1)*HD + t], acc);
        acc = fmaf(a2, hr[(size_t)(n+2)*HD + t], acc);
        acc = fmaf(a3, hr[(size_t)(n+3)*HD + t], acc);
    }
    for (; n < hi; n++) acc = fmaf(gate[n], hr[(size_t)n*HD + t], acc);
    hs[t] = acc;
    out_hg[g*HD + t] = acc;
    __syncthreads();
    // ---- classifier ----
    int f1 = dcode[3], f2 = dcode[4], db = dcode[5];
    float a2c = ldf3(b1, t, db);
    if (f1 == 1){
        const bf16* wm = (const bf16*)W1;
        for (int k = 0; k < HD; k++) a2c += hs[k]*b2f(wm[(size_t)k*HD + t]);
    } else if (f1 == 2){
        const __half* wm = (const __half*)W1;
        for (int k = 0; k < HD; k++) a2c += hs[k]*__half2float(wm[(size_t)k*HD + t]);
    } else {
        const float* wm = (const float*)W1;
        for (int k = 0; k < HD; k++) a2c += hs[k]*wm[(size_t)k*HD + t];
    }
    float p0 = a2c * ldf3(W2, t*CC + 0, f2);
    float p1 = a2c * ldf3(W2, t*CC + 1, f2);
    __shared__ float r0[256], r1[256];
    r0[t] = p0; r1[t] = p1; __syncthreads();
    for (int s = 128; s; s >>= 1){
        if (t < s){ r0[t] += r0[t+s]; r1[t] += r1[t+s]; }
        __syncthreads();
    }
    if (t == 0){
        out0[g*CC+0] = 1.f/(1.f + expf(-(r0[0] + ldf3(b2, 0, db))));
        out0[g*CC+1] = 1.f/(1.f + expf(-(r1[0] + ldf3(b2, 1, db))));
    }
}

extern "C" void kernel_launch(void* const* d_in, const int* in_sizes, int n_in,
                              void* d_out, int out_size, void* d_ws, size_t ws_size,
                              hipStream_t stream) {
    const void* h      = d_in[0];
    const void* src_r  = d_in[1];
    const void* dst_r  = d_in[2];
    const void* gid_r  = d_in[3];
    const void* W_conv = d_in[4];
    const void* b_conv = d_in[5];
    const void* w_gate = d_in[6];
    const void* b_gate = d_in[7];
    const void* W1     = d_in[8];
    const void* b1     = d_in[9];
    const void* W2     = d_in[10];
    const void* b2     = d_in[11];

    float* out     = (float*)d_out;      // fp32 output (established R10)
    float* out0    = out;                // [G,C]
    float* out_att = out + GG*CC;        // [N]
    float* out_hg  = out + GG*CC + NN;   // [G,H]

    char* w = (char*)d_ws;
    float* hr   = (float*)w;  w += (size_t)NN*HD*sizeof(float);
    bf16*  hn   = (bf16*)w;   w += (size_t)NN*HD*sizeof(bf16);
    bf16*  Wb   = (bf16*)w;   w += (size_t)IND*HD*sizeof(bf16);
    float* rs_o = (float*)w;  w += (size_t)NN*sizeof(float);
    float* rs_i = (float*)w;  w += (size_t)NN*sizeof(float);
    float* gate = (float*)w;  w += (size_t)NN*sizeof(float);
    int* gstart = (int*)w;    w += GG*sizeof(int);
    int* gend   = (int*)w;    w += GG*sizeof(int);
    int* dcode  = (int*)w;    w += 8*sizeof(int);
    int* icode  = (int*)w;    w += 8*sizeof(int);
    int* gid_i  = (int*)w;    w += (size_t)NN*sizeof(int);
    int* cnt_out= (int*)w;    w += (size_t)NN*sizeof(int);
    int* cnt_in = (int*)w;    w += (size_t)NN*sizeof(int);
    int* cursor = (int*)w;    w += (size_t)NN*sizeof(int);
    int* rowst  = (int*)w;    w += (size_t)(NN+1)*sizeof(int);
    int* csr    = (int*)w;    w += (size_t)EE*sizeof(int);

    // detection + zero counters (cnt_out|cnt_in|cursor contiguous)
    k_detect<<<64, 256, 0, stream>>>(src_r, dst_r, gid_r,
                                     (const unsigned short*)h, (const unsigned short*)W_conv,
                                     (const unsigned short*)w_gate, (const unsigned short*)W1,
                                     (const unsigned short*)W2, (const unsigned short*)b_conv,
                                     icode, dcode, cnt_out);

    k_prep<<<(EE+255)/256, 256, 0, stream>>>(src_r, dst_r, gid_r, icode,
                                             gid_i, cnt_out, cnt_in);
    k_scan<<<1, 1024, 0, stream>>>(cnt_out, cnt_in, gid_i, rs_o, rs_i,
                                   rowst, gstart, gend);
    k_fill<<<(EE+255)/256, 256, 0, stream>>>(src_r, dst_r, icode, rowst, cursor, csr);

    k_wprep<<<IND, HD, 0, stream>>>(W_conv, dcode, Wb);
    k_gemm1m<<<NN/32, 256, 0, stream>>>(h, Wb, rs_o, dcode, hn);

    k_gather<<<(NN+3)/4, 256, 0, stream>>>(hn, rs_i, rowst, csr,
                                           b_conv, w_gate, b_gate, dcode, hr, gate);

    k_tail<<<GG, 256, 0, stream>>>(gstart, gend, gate, hr,
                                   W1, b1, W2, b2, dcode, out0, out_att, out_hg);
}

// Round 18
// 251.476 us; speedup vs baseline: 1.0542x; 1.0542x over previous
//
#include <hip/hip_runtime.h>
#include <hip/hip_bf16.h>
#include <hip/hip_fp16.h>
#include <math.h>

#define NN 20000
#define EE 320000
#define GG 64
#define IND 256
#define HD 256
#define CC 2

typedef __hip_bfloat16 bf16;
typedef __attribute__((ext_vector_type(8))) short short8;
typedef __attribute__((ext_vector_type(4))) float f32x4;

__device__ __forceinline__ float b2f(bf16 x){ return __bfloat162float(x); }
__device__ __forceinline__ float bits2f(unsigned short b){
    union{ float f; unsigned u; } v; v.u = ((unsigned)b) << 16; return v.f;
}
__device__ __forceinline__ short f2bs(float x){
    union{ bf16 b; short s; } u; u.b = __float2bfloat16(x); return u.s;
}
// float load by code: 0=fp32, 1=bf16, 2=fp16
__device__ __forceinline__ float ldf3(const void* p, size_t i, int c){
    if (c == 1) return b2f(((const bf16*)p)[i]);
    if (c == 2) return __half2float(((const __half*)p)[i]);
    return ((const float*)p)[i];
}
__device__ __forceinline__ int idec(const void* p, int i, int c){
    if (c == 1) return (int)(((const long long*)p)[i]);
    if (c == 2) return (int)(((const float*)p)[i]);
    if (c == 3) return (int)__half2float(((const __half*)p)[i]);
    return ((const int*)p)[i];
}

// ---- merged dtype + int-format detection + workspace zeroing ----
// blocks 0..2: int format of src/dst/gid; block 3: float dtypes;
// blocks 4+: zero counters (3*NN ints) + hg (GG*HD floats), contiguous.
__global__ __launch_bounds__(256) void k_detect(const void* src, const void* dst,
                         const void* gid,
                         const unsigned short* h, const unsigned short* Wc,
                         const unsigned short* wg, const unsigned short* W1,
                         const unsigned short* W2, const unsigned short* bc,
                         int* icode, int* dcode, int* zero_base){
    int blk = blockIdx.x;
    if (blk >= 4){
        int idx = (blk-4)*256 + threadIdx.x;
        const int total = 3*NN + GG*HD;
        for (int i = idx; i < total; i += 60*256) zero_base[i] = 0;
        return;
    }
    if (blk < 3){
        if (threadIdx.x != 0) return;
        const void* buf = (blk == 0) ? src : (blk == 1) ? dst : gid;
        int n     = (blk == 2) ? NN : EE;
        int bound = (blk == 2) ? GG : NN;
        int ok64 = 1, ok32 = 1, okf32 = 1, okf16 = 1;
        const long long* p64 = (const long long*)buf;
        for (int i = 0; i < 64; i++){
            long long v = p64[n/8 + i];
            if (v < 0 || v >= (long long)bound) ok64 = 0;
        }
        const int* p32 = (const int*)buf;
        const unsigned* pu = (const unsigned*)buf;
        for (int i = 0; i < 64; i++){
            int v = p32[n/4 + i];
            if (v < 0 || v >= bound) ok32 = 0;
            float f = __uint_as_float(pu[n/4 + i]);
            if (!(f >= 0.f && f < (float)bound)) okf32 = 0;
        }
        const __half* ph = (const __half*)buf;
        for (int i = 0; i < 64; i++){
            float f = __half2float(ph[n/2 + i]);
            if (!(f >= 0.f && f < (float)bound)) okf16 = 0;
        }
        icode[blk] = ok64 ? 1 : (ok32 ? 0 : (okf32 ? 2 : (okf16 ? 3 : 0)));
    } else {
        int t = threadIdx.x; if (t >= 6) return;
        const unsigned short* p = t==0?h:t==1?Wc:t==2?wg:t==3?W1:t==4?W2:bc;
        int cb = 0, cf = 0, nz = 0;
        for (int i = 0; i < 128; i += 2){
            unsigned u = p[i];
            nz += (u != 0);
            int e8 = (u >> 7) & 0xFF;
            int e5 = (u >> 10) & 0x1F;
            cb += (e8 >= 100 && e8 <= 141);
            cf += (e5 >= 4 && e5 <= 22);
        }
        dcode[t] = (nz < 8) ? 0 : (cb >= 60) ? 1 : ((cf >= 60) ? 2 : 0);
    }
}

// decode gid + int degree counting
__global__ void k_prep(const void* src_r, const void* dst_r, const void* gid_r,
                       const int* __restrict__ icode,
                       int* __restrict__ gid_i,
                       int* cnt_out, int* cnt_in){
    int i = blockIdx.x*256 + threadIdx.x;
    if (i < NN) gid_i[i] = idec(gid_r, i, icode[2]);
    if (i >= EE) return;
    int s = idec(src_r, i, icode[0]);
    int d = idec(dst_r, i, icode[1]);
    if ((unsigned)s < NN) atomicAdd(&cnt_out[s], 1);
    if ((unsigned)d < NN) atomicAdd(&cnt_in[d], 1);
}

// single-block (1024 threads): rs arrays + scan -> rowst + per-graph ranges
__global__ __launch_bounds__(1024) void k_scan(const int* __restrict__ cnt_out,
                                               const int* __restrict__ cnt_in,
                                               const int* __restrict__ gid,
                                               float* rs_out, float* rs_in,
                                               int* __restrict__ row_start,
                                               int* gstart, int* gend){
    int t = threadIdx.x;
    for (int i = t; i < NN; i += 1024){
        rs_out[i] = rsqrtf(fmaxf((float)cnt_out[i], 1.f));
        rs_in[i]  = rsqrtf(fmaxf((float)cnt_in[i], 1.f));
    }
    __shared__ int part[1024];
    const int per = (NN + 1023)/1024;
    int lo = t*per, hi = min(lo+per, NN);
    int s = 0;
    for (int i = lo; i < hi; i++) s += cnt_in[i];
    part[t] = s; __syncthreads();
    for (int off = 1; off < 1024; off <<= 1){
        int v = (t >= off) ? part[t-off] : 0;
        __syncthreads();
        part[t] += v;
        __syncthreads();
    }
    int base = part[t] - s;
    for (int i = lo; i < hi; i++){ row_start[i] = base; base += cnt_in[i]; }
    if (t == 1023) row_start[NN] = part[1023];
    __shared__ int ls[GG+1];
    if (t <= GG){
        int a = 0, b = NN;
        while (a < b){
            int mid = (a + b) >> 1;
            if (gid[mid] < t) a = mid + 1; else b = mid;
        }
        ls[t] = a;
    }
    __syncthreads();
    if (t < GG){ gstart[t] = ls[t]; gend[t] = ls[t+1]; }
}

// fill CSR, decoding raw edges inline
__global__ void k_fill(const void* src_r, const void* dst_r,
                       const int* __restrict__ icode,
                       const int* __restrict__ row_start, int* __restrict__ cursor,
                       int* __restrict__ csr_src){
    int e = blockIdx.x*256 + threadIdx.x;
    if (e >= EE) return;
    int s = idec(src_r, e, icode[0]);
    int d = idec(dst_r, e, icode[1]);
    if ((unsigned)s >= NN || (unsigned)d >= NN) return;
    int pos = atomicAdd(&cursor[d], 1);
    csr_src[row_start[d] + pos] = s;
}

// W_conv[IN][HD] fp32 -> Wb[n][k] bf16 (fragment-friendly transpose)
__global__ void k_wprep(const void* __restrict__ W, const int* __restrict__ dcode,
                        bf16* __restrict__ Wb){
    int k = blockIdx.x;
    int n = threadIdx.x;
    Wb[(size_t)n*IND + k] = __float2bfloat16(ldf3(W, (size_t)k*HD + n, dcode[1]));
}

// LDS-free MFMA GEMM: hn[N,HD] = rs_out[n]*(h @ W_conv), 32 rows/block, 625 blocks.
__global__ __launch_bounds__(256) void k_gemm1m(const void* __restrict__ h,
                                                const bf16* __restrict__ Wb,
                                                const float* __restrict__ rs_out,
                                                const int* __restrict__ dcode,
                                                bf16* __restrict__ hn){
    int fh = dcode[0];
    int tid = threadIdx.x;
    int wave = tid >> 6, lane = tid & 63;
    int q = lane >> 4, mr = lane & 15;
    int row0 = blockIdx.x * 32;
    int ncol0 = wave * 64;
    f32x4 acc[2][4] = {};
    const float* hf = (const float*)h;
    #pragma unroll
    for (int k0 = 0; k0 < IND; k0 += 32){
        short8 a[2], b[4];
        if (fh == 0){
            #pragma unroll
            for (int mi = 0; mi < 2; mi++){
                int r = row0 + mi*16 + mr;
                const float4* p = (const float4*)(hf + (size_t)r*IND + k0 + q*8);
                float4 v0 = p[0], v1 = p[1];
                a[mi][0] = f2bs(v0.x); a[mi][1] = f2bs(v0.y);
                a[mi][2] = f2bs(v0.z); a[mi][3] = f2bs(v0.w);
                a[mi][4] = f2bs(v1.x); a[mi][5] = f2bs(v1.y);
                a[mi][6] = f2bs(v1.z); a[mi][7] = f2bs(v1.w);
            }
        } else {
            #pragma unroll
            for (int mi = 0; mi < 2; mi++){
                int r = row0 + mi*16 + mr;
                #pragma unroll
                for (int j = 0; j < 8; j++)
                    a[mi][j] = f2bs(ldf3(h, (size_t)r*IND + k0 + q*8 + j, fh));
            }
        }
        #pragma unroll
        for (int ni = 0; ni < 4; ni++)
            b[ni] = *reinterpret_cast<const short8*>(
                        Wb + (size_t)(ncol0 + ni*16 + mr)*IND + k0 + q*8);
        #pragma unroll
        for (int mi = 0; mi < 2; mi++)
            #pragma unroll
            for (int ni = 0; ni < 4; ni++)
                acc[mi][ni] = __builtin_amdgcn_mfma_f32_16x16x32_bf16(
                                  a[mi], b[ni], acc[mi][ni], 0, 0, 0);
    }
    #pragma unroll
    for (int mi = 0; mi < 2; mi++){
        int rowb = row0 + mi*16 + q*4;
        #pragma unroll
        for (int r = 0; r < 4; r++){
            int row = rowb + r;
            float rs = rs_out[row];
            #pragma unroll
            for (int ni = 0; ni < 4; ni++)
                hn[(size_t)row*HD + ncol0 + ni*16 + mr] =
                    __float2bfloat16(acc[mi][ni][r] * rs);
        }
    }
}

// fused gather + epilogue: one wave per dst node; 8-wide MLP unroll.
__global__ __launch_bounds__(256) void k_gather(const bf16* __restrict__ hn,
                                                const float* __restrict__ rs_in,
                                                const int* __restrict__ row_start,
                                                const int* __restrict__ csr_src,
                                                const void* __restrict__ b_conv,
                                                const void* __restrict__ w_gate,
                                                const void* __restrict__ b_gate,
                                                const int* __restrict__ dcode,
                                                float* __restrict__ hr,
                                                float* __restrict__ gate){
    int wave = threadIdx.x >> 6, lane = threadIdx.x & 63;
    int n = blockIdx.x*4 + wave;
    if (n >= NN) return;
    int lo = row_start[n], hi = row_start[n+1];
    float ax = 0.f, ay = 0.f, az = 0.f, aw = 0.f;
    int j = lo;
    for (; j + 8 <= hi; j += 8){
        int s0 = csr_src[j+0], s1 = csr_src[j+1], s2 = csr_src[j+2], s3 = csr_src[j+3];
        int s4 = csr_src[j+4], s5 = csr_src[j+5], s6 = csr_src[j+6], s7 = csr_src[j+7];
        ushort4 u0 = ((const ushort4*)(hn + (size_t)s0*HD))[lane];
        ushort4 u1 = ((const ushort4*)(hn + (size_t)s1*HD))[lane];
        ushort4 u2 = ((const ushort4*)(hn + (size_t)s2*HD))[lane];
        ushort4 u3 = ((const ushort4*)(hn + (size_t)s3*HD))[lane];
        ushort4 u4 = ((const ushort4*)(hn + (size_t)s4*HD))[lane];
        ushort4 u5 = ((const ushort4*)(hn + (size_t)s5*HD))[lane];
        ushort4 u6 = ((const ushort4*)(hn + (size_t)s6*HD))[lane];
        ushort4 u7 = ((const ushort4*)(hn + (size_t)s7*HD))[lane];
        ax += bits2f(u0.x)+bits2f(u1.x)+bits2f(u2.x)+bits2f(u3.x)
            + bits2f(u4.x)+bits2f(u5.x)+bits2f(u6.x)+bits2f(u7.x);
        ay += bits2f(u0.y)+bits2f(u1.y)+bits2f(u2.y)+bits2f(u3.y)
            + bits2f(u4.y)+bits2f(u5.y)+bits2f(u6.y)+bits2f(u7.y);
        az += bits2f(u0.z)+bits2f(u1.z)+bits2f(u2.z)+bits2f(u3.z)
            + bits2f(u4.z)+bits2f(u5.z)+bits2f(u6.z)+bits2f(u7.z);
        aw += bits2f(u0.w)+bits2f(u1.w)+bits2f(u2.w)+bits2f(u3.w)
            + bits2f(u4.w)+bits2f(u5.w)+bits2f(u6.w)+bits2f(u7.w);
    }
    for (; j < hi; j++){
        int s = csr_src[j];
        ushort4 u = ((const ushort4*)(hn + (size_t)s*HD))[lane];
        ax += bits2f(u.x); ay += bits2f(u.y); az += bits2f(u.z); aw += bits2f(u.w);
    }
    int db = dcode[5], fg = dcode[2];
    float rsn = rs_in[n];
    int c = lane*4;
    ax = fmaxf(fmaf(ax, rsn, ldf3(b_conv, c+0, db)), 0.f);
    ay = fmaxf(fmaf(ay, rsn, ldf3(b_conv, c+1, db)), 0.f);
    az = fmaxf(fmaf(az, rsn, ldf3(b_conv, c+2, db)), 0.f);
    aw = fmaxf(fmaf(aw, rsn, ldf3(b_conv, c+3, db)), 0.f);
    float4 v; v.x = ax; v.y = ay; v.z = az; v.w = aw;
    ((float4*)(hr + (size_t)n*HD))[lane] = v;
    float g = ax*ldf3(w_gate, c+0, fg) + ay*ldf3(w_gate, c+1, fg)
            + az*ldf3(w_gate, c+2, fg) + aw*ldf3(w_gate, c+3, fg);
    #pragma unroll
    for (int off = 32; off; off >>= 1) g += __shfl_down(g, off);
    if (lane == 0) gate[n] = g + ldf3(b_gate, 0, db);
}

// segment softmax: one block per graph; no atomics
__global__ __launch_bounds__(256) void k_soft(const int* __restrict__ gstart,
                                              const int* __restrict__ gend,
                                              float* __restrict__ gate,
                                              float* __restrict__ out_att){
    int g = blockIdx.x, t = threadIdx.x;
    int lo = gstart[g], hi = gend[g];
    if (lo >= hi) return;
    __shared__ float sm[256];
    float m = -INFINITY;
    for (int n = lo + t; n < hi; n += 256) m = fmaxf(m, gate[n]);
    sm[t] = m; __syncthreads();
    for (int s = 128; s; s >>= 1){ if (t < s) sm[t] = fmaxf(sm[t], sm[t+s]); __syncthreads(); }
    m = sm[0]; __syncthreads();
    float acc = 0.f;
    for (int n = lo + t; n < hi; n += 256){
        float e = expf(gate[n] - m);
        gate[n] = e;
        acc += e;
    }
    sm[t] = acc; __syncthreads();
    for (int s = 128; s; s >>= 1){ if (t < s) sm[t] += sm[t+s]; __syncthreads(); }
    float inv = 1.f / sm[0];
    for (int n = lo + t; n < hi; n += 256){
        float a = gate[n] * inv;
        gate[n] = a;
        out_att[n] = a;
    }
}

// attention pool: 8-way split per graph, atomic merge (512 blocks)
__global__ __launch_bounds__(256) void k_hg(const float* __restrict__ att,
                                            const float* __restrict__ hr,
                                            const int* __restrict__ gstart,
                                            const int* __restrict__ gend,
                                            float* __restrict__ hg){
    int g = blockIdx.x >> 3, part = blockIdx.x & 7;
    int c = threadIdx.x;
    int s = gstart[g], en = gend[g];
    int len = en - s;
    if (len <= 0) return;
    int chunk = (len + 7) >> 3;
    int lo = s + part*chunk, hi = min(lo + chunk, en);
    if (lo >= hi) return;
    float acc = 0.f;
    for (int n = lo; n < hi; n++) acc += att[n] * hr[(size_t)n*HD + c];
    atomicAdd(&hg[g*HD + c], acc);
}

__global__ __launch_bounds__(256) void k_cls(const float* __restrict__ hg,
                                             const void* __restrict__ W1,
                                             const void* __restrict__ b1,
                                             const void* __restrict__ W2,
                                             const void* __restrict__ b2,
                                             const int* __restrict__ dcode,
                                             float* __restrict__ out0,
                                             float* __restrict__ out_hg){
    int f1 = dcode[3], f2 = dcode[4], db = dcode[5];
    int g = blockIdx.x, tid = threadIdx.x;
    __shared__ float hs[256];
    float hv = hg[g*HD + tid];
    hs[tid] = hv;
    out_hg[g*HD + tid] = hv;
    __syncthreads();
    float acc = ldf3(b1, tid, db);
    if (f1 == 1){
        const bf16* w = (const bf16*)W1;
        for (int k = 0; k < HD; k++) acc += hs[k]*b2f(w[(size_t)k*HD + tid]);
    } else if (f1 == 2){
        const __half* w = (const __half*)W1;
        for (int k = 0; k < HD; k++) acc += hs[k]*__half2float(w[(size_t)k*HD + tid]);
    } else {
        const float* w = (const float*)W1;
        for (int k = 0; k < HD; k++) acc += hs[k]*w[(size_t)k*HD + tid];
    }
    float p0 = acc * ldf3(W2, tid*CC + 0, f2);
    float p1 = acc * ldf3(W2, tid*CC + 1, f2);
    __shared__ float r0[256], r1[256];
    r0[tid] = p0; r1[tid] = p1; __syncthreads();
    for (int s = 128; s; s >>= 1){
        if (tid < s){ r0[tid] += r0[tid+s]; r1[tid] += r1[tid+s]; }
        __syncthreads();
    }
    if (tid == 0){
        out0[g*CC+0] = 1.f/(1.f + expf(-(r0[0] + ldf3(b2, 0, db))));
        out0[g*CC+1] = 1.f/(1.f + expf(-(r1[0] + ldf3(b2, 1, db))));
    }
}

extern "C" void kernel_launch(void* const* d_in, const int* in_sizes, int n_in,
                              void* d_out, int out_size, void* d_ws, size_t ws_size,
                              hipStream_t stream) {
    const void* h      = d_in[0];
    const void* src_r  = d_in[1];
    const void* dst_r  = d_in[2];
    const void* gid_r  = d_in[3];
    const void* W_conv = d_in[4];
    const void* b_conv = d_in[5];
    const void* w_gate = d_in[6];
    const void* b_gate = d_in[7];
    const void* W1     = d_in[8];
    const void* b1     = d_in[9];
    const void* W2     = d_in[10];
    const void* b2     = d_in[11];

    float* out     = (float*)d_out;      // fp32 output (established R10)
    float* out0    = out;                // [G,C]
    float* out_att = out + GG*CC;        // [N]
    float* out_hg  = out + GG*CC + NN;   // [G,H]

    char* w = (char*)d_ws;
    float* hr   = (float*)w;  w += (size_t)NN*HD*sizeof(float);
    bf16*  hn   = (bf16*)w;   w += (size_t)NN*HD*sizeof(bf16);
    bf16*  Wb   = (bf16*)w;   w += (size_t)IND*HD*sizeof(bf16);
    float* rs_o = (float*)w;  w += (size_t)NN*sizeof(float);
    float* rs_i = (float*)w;  w += (size_t)NN*sizeof(float);
    float* gate = (float*)w;  w += (size_t)NN*sizeof(float);
    int* gstart = (int*)w;    w += GG*sizeof(int);
    int* gend   = (int*)w;    w += GG*sizeof(int);
    int* dcode  = (int*)w;    w += 8*sizeof(int);
    int* icode  = (int*)w;    w += 8*sizeof(int);
    int* gid_i  = (int*)w;    w += (size_t)NN*sizeof(int);
    // contiguous zero region: cnt_out | cnt_in | cursor | hg
    int* cnt_out= (int*)w;    w += (size_t)NN*sizeof(int);
    int* cnt_in = (int*)w;    w += (size_t)NN*sizeof(int);
    int* cursor = (int*)w;    w += (size_t)NN*sizeof(int);
    float* hg   = (float*)w;  w += (size_t)GG*HD*sizeof(float);
    int* rowst  = (int*)w;    w += (size_t)(NN+1)*sizeof(int);
    int* csr    = (int*)w;    w += (size_t)EE*sizeof(int);

    // detection + zeroing (counters + hg)
    k_detect<<<64, 256, 0, stream>>>(src_r, dst_r, gid_r,
                                     (const unsigned short*)h, (const unsigned short*)W_conv,
                                     (const unsigned short*)w_gate, (const unsigned short*)W1,
                                     (const unsigned short*)W2, (const unsigned short*)b_conv,
                                     icode, dcode, cnt_out);

    k_prep<<<(EE+255)/256, 256, 0, stream>>>(src_r, dst_r, gid_r, icode,
                                             gid_i, cnt_out, cnt_in);
    k_scan<<<1, 1024, 0, stream>>>(cnt_out, cnt_in, gid_i, rs_o, rs_i,
                                   rowst, gstart, gend);
    k_fill<<<(EE+255)/256, 256, 0, stream>>>(src_r, dst_r, icode, rowst, cursor, csr);

    k_wprep<<<IND, HD, 0, stream>>>(W_conv, dcode, Wb);
    k_gemm1m<<<NN/32, 256, 0, stream>>>(h, Wb, rs_o, dcode, hn);

    k_gather<<<(NN+3)/4, 256, 0, stream>>>(hn, rs_i, rowst, csr,
                                           b_conv, w_gate, b_gate, dcode, hr, gate);

    k_soft<<<GG, 256, 0, stream>>>(gstart, gend, gate, out_att);
    k_hg<<<GG*8, 256, 0, stream>>>(gate, hr, gstart, gend, hg);
    k_cls<<<GG, 256, 0, stream>>>(hg, W1, b1, W2, b2, dcode, out0, out_hg);
}